// Round 1
// 294.708 us; speedup vs baseline: 1.4211x; 1.4211x over previous
//
#include <hip/hip_runtime.h>

#define SEQ 550
#define MID 100
#define TPB 256

typedef _Float16 half2_t __attribute__((ext_vector_type(2)));

union H2I { int i; half2_t h; ushort2 u2; };

__device__ __forceinline__ float fdot2(half2_t a, half2_t b, float c) {
    return __builtin_amdgcn_fdot2(a, b, c, false);
}
__device__ __forceinline__ float sigm(float x) { return 1.0f / (1.0f + __expf(-x)); }
__device__ __forceinline__ float tanh_f(float x) { return 1.0f - 2.0f / (__expf(2.0f * x) + 1.0f); }
__device__ __forceinline__ half2_t i2h(int v) { H2I u; u.i = v; return u.h; }

// sum of adjacent lane pair via DPP quad_perm [1,0,3,2] — VALU only, no LDS
__device__ __forceinline__ float pair_sum(float x) {
    int yi = __builtin_amdgcn_update_dpp(0, __float_as_int(x), 0xB1, 0xF, 0xF, true);
    return x + __int_as_float(yi);
}

__global__ __launch_bounds__(TPB, 1) void gru_fused(
    const int*   __restrict__ x,
    const float* __restrict__ hidden,
    const float* __restrict__ embed,
    const float* __restrict__ w_ih,
    const float* __restrict__ w_hh,
    const float* __restrict__ b_ih,
    const float* __restrict__ b_hh,
    const float* __restrict__ fc_w,
    const float* __restrict__ fc_b,
    float*       __restrict__ out)
{
    // per t: 16 ushorts (32B): halves 0..5 at slots 0..5 (p0), halves 6..9 at slots 8..11 (p1),
    // slots 12..13 zeroed (multiplied by zero weight), 6..7,14..15 never used in arithmetic.
    __shared__ __align__(16) ushort seqbuf[SEQ * 16];   // 17.6 KB
    // double-buffered h as fp16: 2 buffers x 256B; each: p0 halves 0..49 at [0,100), p1 at [128,228)
    __shared__ __align__(16) int hbuf[128];
    __shared__ float partial[MID];

    const int  tid = threadIdx.x;
    const bool act = tid < 2 * MID;   // 200 working threads: pair (2u, 2u+1) owns unit u
    const int  u   = tid >> 1;
    const int  p   = tid & 1;         // p=0: cols [0,50) + emb cols [0,6); p=1: cols [50,100) + emb cols [6,10)
    const int  hidx = (u < 50) ? u : u + 14;   // ushort index of unit u within one h buffer

    // ---- stage embedded sequence as fp16 ----
    for (int i = tid; i < SEQ * 10; i += TPB) {
        int t = i / 10;
        int k = i - 10 * t;
        H2I c; c.h = half2_t{(_Float16)embed[x[t] * 10 + k], (_Float16)0.0f};
        seqbuf[t * 16 + (k < 6 ? k : k + 2)] = c.u2.x;
    }
    for (int i = tid; i < SEQ; i += TPB)
        *(int*)(seqbuf + i * 16 + 12) = 0;   // zero the pad slots p1's third fdot2 touches

    // ---- per-thread weights in registers (fp16 pairs): 3 gate rows of unit u, half columns ----
    half2_t whh[3][25];
    half2_t wihr[3][3];
    float b0 = 0.f, b1 = 0.f, b2 = 0.f, b3 = 0.f;
    float hreg = 0.f, fcw = 0.f;

    if (act) {
        #pragma unroll
        for (int r = 0; r < 3; r++) {
            const int row = r * MID + u;
            const float2* wr = (const float2*)(w_hh + row * MID) + 25 * p;
            #pragma unroll
            for (int k = 0; k < 25; k++) {
                float2 f = wr[k];
                whh[r][k] = half2_t{(_Float16)f.x, (_Float16)f.y};
            }
            const float* wi = w_ih + row * 10 + 6 * p;
            wihr[r][0] = half2_t{(_Float16)wi[0], (_Float16)wi[1]};
            wihr[r][1] = half2_t{(_Float16)wi[2], (_Float16)wi[3]};
            if (p == 0) wihr[r][2] = half2_t{(_Float16)wi[4], (_Float16)wi[5]};
            else        wihr[r][2] = half2_t{(_Float16)0.0f, (_Float16)0.0f};
        }
        if (p == 0) {   // biases counted once per pair
            b0 = b_ih[u]           + b_hh[u];
            b1 = b_ih[MID + u]     + b_hh[MID + u];
            b2 = b_ih[2 * MID + u];            // input side of n-gate
            b3 = b_hh[2 * MID + u];            // hidden side of n-gate (gets r-scaled)
        }
        hreg = hidden[u];
        fcw  = fc_w[u];
        if (p == 0) ((_Float16*)hbuf)[hidx] = (_Float16)hreg;   // init buffer 0
    }
    float fcb = (tid == 0) ? fc_b[0] : 0.0f;

    __syncthreads();

    #pragma unroll 1
    for (int t = 0; t < SEQ; t++) {
        if (act) {
            // ---- read my half of h: 2 broadcast addresses per ds_read, conflict-free ----
            const int   rbase = ((t & 1) << 8) + (p << 7);           // byte offset of read region
            const int4* hp4   = (const int4*)((const char*)hbuf + rbase);
            int4 q0 = hp4[0], q1 = hp4[1], q2 = hp4[2], q3 = hp4[3], q4 = hp4[4], q5 = hp4[5];
            int  qe = ((const int*)hp4)[24];
            int4 ev = *(const int4*)(seqbuf + t * 16 + p * 8);       // my 3 emb half2s (+pad)

            half2_t hh[25];
            hh[0]=i2h(q0.x);  hh[1]=i2h(q0.y);  hh[2]=i2h(q0.z);  hh[3]=i2h(q0.w);
            hh[4]=i2h(q1.x);  hh[5]=i2h(q1.y);  hh[6]=i2h(q1.z);  hh[7]=i2h(q1.w);
            hh[8]=i2h(q2.x);  hh[9]=i2h(q2.y);  hh[10]=i2h(q2.z); hh[11]=i2h(q2.w);
            hh[12]=i2h(q3.x); hh[13]=i2h(q3.y); hh[14]=i2h(q3.z); hh[15]=i2h(q3.w);
            hh[16]=i2h(q4.x); hh[17]=i2h(q4.y); hh[18]=i2h(q4.z); hh[19]=i2h(q4.w);
            hh[20]=i2h(q5.x); hh[21]=i2h(q5.y); hh[22]=i2h(q5.z); hh[23]=i2h(q5.w);
            hh[24]=i2h(qe);

            // ---- half-dots for the 3 gate rows of my unit ----
            float s0 = b0, s1 = b1, s2 = b2, s3 = b3;
            #pragma unroll
            for (int k = 0; k < 25; k++) {
                s0 = fdot2(whh[0][k], hh[k], s0);   // r row (hidden)
                s1 = fdot2(whh[1][k], hh[k], s1);   // z row (hidden)
                s3 = fdot2(whh[2][k], hh[k], s3);   // n row (hidden, kept separate for r-scale)
            }
            half2_t e0 = i2h(ev.x), e1 = i2h(ev.y), e2 = i2h(ev.z);
            s0 = fdot2(wihr[0][0], e0, s0); s0 = fdot2(wihr[0][1], e1, s0); s0 = fdot2(wihr[0][2], e2, s0);
            s1 = fdot2(wihr[1][0], e0, s1); s1 = fdot2(wihr[1][1], e1, s1); s1 = fdot2(wihr[1][2], e2, s1);
            s2 = fdot2(wihr[2][0], e0, s2); s2 = fdot2(wihr[2][1], e1, s2); s2 = fdot2(wihr[2][2], e2, s2);

            // ---- combine pair halves in-register (no gates buffer, no second barrier) ----
            float ar  = pair_sum(s0);
            float az  = pair_sum(s1);
            float gin = pair_sum(s2);
            float ghn = pair_sum(s3);

            float r = sigm(ar);
            float z = sigm(az);
            float n = tanh_f(gin + r * ghn);
            hreg = n + z * (hreg - n);              // exact fp32 state
            if (p == 0)
                ((_Float16*)hbuf)[(((t & 1) ^ 1) << 7) + hidx] = (_Float16)hreg;
        }
        __syncthreads();   // single barrier per step; double buffer makes read/write race-free
    }

    // ---- epilogue: sigmoid(relu(h) . fc_w + fc_b) ----
    if (act && p == 0) partial[u] = fmaxf(hreg, 0.0f) * fcw;
    __syncthreads();
    if (tid == 0) {
        float s = fcb;
        const float4* pp = (const float4*)partial;
        #pragma unroll
        for (int k = 0; k < 25; k++) {
            float4 f = pp[k];
            s += (f.x + f.y) + (f.z + f.w);
        }
        out[0] = sigm(s);
    }
}

extern "C" void kernel_launch(void* const* d_in, const int* in_sizes, int n_in,
                              void* d_out, int out_size, void* d_ws, size_t ws_size,
                              hipStream_t stream) {
    const int*   x      = (const int*)  d_in[0];
    const float* hidden = (const float*)d_in[1];
    const float* embed  = (const float*)d_in[2];
    const float* w_ih   = (const float*)d_in[3];
    const float* w_hh   = (const float*)d_in[4];
    const float* b_ih   = (const float*)d_in[5];
    const float* b_hh   = (const float*)d_in[6];
    const float* fc_w   = (const float*)d_in[7];
    const float* fc_b   = (const float*)d_in[8];
    float*       out    = (float*)d_out;

    gru_fused<<<1, TPB, 0, stream>>>(x, hidden, embed, w_ih, w_hh,
                                     b_ih, b_hh, fc_w, fc_b, out);
}